// Round 8
// baseline (380.751 us; speedup 1.0000x reference)
//
#include <hip/hip_runtime.h>
#include <hip/hip_bf16.h>

// EfficientAttention: B=8 N=4096 C=768 H=12 D=64, M = 32768
// prep (cast + bias) -> gemm_rb<QKV,BM256> (q-softmax epilogue; k,v fp16)
//   -> kv_partial (private split buffers) -> weff_build -> gemm_rb<OUT,BM128>
// R8 GEMM: ring-4 LDS buffers, BK=32, ONE barrier + ONE counted vmcnt gate per
// K-tile (no intra-tile phase barriers -> waves skew, LDS-read pipe overlaps MFMA
// pipe). stage(t+3) targets buf (t+3)&3, disjoint from live bufs t..t+2.
// Bijective chunk swizzle (row&3)^((row>>2)&3): every b128 read covers a 1KB
// region once -> all 32 banks balanced. Source-side pre-swizzle (rule 21).
// T1 XCD swizzle, T5 setprio. Compiler manages lgkm (no inline lgkm pins).

#define AS1 __attribute__((address_space(1)))
#define AS3 __attribute__((address_space(3)))

typedef __attribute__((ext_vector_type(8))) short    s16x8;
typedef __attribute__((ext_vector_type(4))) float    f32x4;
typedef __attribute__((ext_vector_type(8))) _Float16 f16x8;
typedef __attribute__((ext_vector_type(4))) unsigned short u16x4;

__device__ __forceinline__ unsigned short f2bf(float f) {
  union { float f; unsigned u; } v; v.f = f;
  unsigned r = v.u + 0x7FFFu + ((v.u >> 16) & 1u);
  return (unsigned short)(r >> 16);
}

// ---------------- prep: cast x + Wq|Wk|Wv -> bf16, concat bias ----------------
__global__ __launch_bounds__(256) void prep(const float* __restrict__ x,
                                            const float* __restrict__ Wq, const float* __restrict__ Wk,
                                            const float* __restrict__ Wv,
                                            const float* __restrict__ bq, const float* __restrict__ bk,
                                            const float* __restrict__ bv,
                                            unsigned short* __restrict__ x_bf,
                                            unsigned short* __restrict__ wqkv_bf,
                                            float* __restrict__ bqkv) {
  const int XB = 2304;
  if ((int)blockIdx.x >= XB) {                    // 9 tail blocks: bias concat
    int j = (blockIdx.x - XB) * 256 + threadIdx.x;
    if (j < 768) bqkv[j] = bq[j];
    else if (j < 1536) bqkv[j] = bk[j - 768];
    else if (j < 2304) bqkv[j] = bv[j - 1536];
    return;
  }
  const int n8x = 3145728, n8w = 73728;
  const int stride = XB * 256;
  for (int i = blockIdx.x * 256 + threadIdx.x; i < n8x + 3 * n8w; i += stride) {
    const float* s; unsigned short* d;
    if (i < n8x) { s = x + (size_t)i * 8; d = x_bf + (size_t)i * 8; }
    else {
      int wi = i - n8x, w = wi / n8w, off = wi - w * n8w;
      const float* ws_ = (w == 0) ? Wq : (w == 1) ? Wk : Wv;
      s = ws_ + (size_t)off * 8; d = wqkv_bf + (size_t)wi * 8;
    }
    f32x4 a = ((const f32x4*)s)[0], b = ((const f32x4*)s)[1];
    u16x4 lo, hi;
    lo[0] = f2bf(a[0]); lo[1] = f2bf(a[1]); lo[2] = f2bf(a[2]); lo[3] = f2bf(a[3]);
    hi[0] = f2bf(b[0]); hi[1] = f2bf(b[1]); hi[2] = f2bf(b[2]); hi[3] = f2bf(b[3]);
    ((u16x4*)d)[0] = lo; ((u16x4*)d)[1] = hi;
  }
}

// ---------------- gemm_rb: C[M,N] = A[M,K] @ Bm[N,K]^T + bias ----------------
// BM = 128*BMBLK, BN = 256, 8 waves (2 wr x 4 wc), wave tile (BM/2) x 64.
// MODE 0: fp32 out (batched B). MODE 1: QKV epilogue (q-softmax / k,v fp16).
template <int MODE, int BMBLK>
__global__ __launch_bounds__(512, 2) void gemm_rb(const unsigned short* __restrict__ A,
                                                  const unsigned short* __restrict__ Bm,
                                                  const float* __restrict__ bias,
                                                  void* out0, void* out1, void* out2,
                                                  int N, int K, int nb, int batchedB) {
  constexpr int BM = BMBLK * 128;
  constexpr int MI = BMBLK * 4;
  __shared__ unsigned short As[4][BM * 32];     // ring-4, BK=32
  __shared__ unsigned short Bs[4][256 * 32];
  const int tid = threadIdx.x, lane = tid & 63, wid = tid >> 6;
  const int wr = wid >> 2, wc = wid & 3;
  const int cpx = gridDim.x >> 3;
  const int logical = (blockIdx.x & 7) * cpx + (blockIdx.x >> 3);
  const int m0 = (logical / nb) * BM, n0 = (logical % nb) * 256;
  const unsigned short* Bp = Bm + (batchedB ? ((size_t)(m0 >> 12) * 589824) : 0);

  f32x4 acc[MI][4] = {};
  // write-side swizzle: row = tid>>2 (mod 128 sweep), phys chunk = tid&3 holds
  // logical chunk (tid&3)^x(row) -> pre-swizzle the global source column.
  const int xw = ((tid >> 2) & 3) ^ ((tid >> 4) & 3);
  const int src_off = ((tid & 3) ^ xw) * 8;

  auto stage = [&](int buf, int k0) {           // BMBLK+2 gload_lds / thread
#pragma unroll
    for (int j = 0; j < BMBLK; ++j) {
      int row = j * 128 + (tid >> 2);
      __builtin_amdgcn_global_load_lds(
          (const AS1 void*)(A + (size_t)(m0 + row) * K + k0 + src_off),
          (AS3 void*)(&As[buf][row * 32 + (tid & 3) * 8]), 16, 0, 0);
    }
#pragma unroll
    for (int j = 0; j < 2; ++j) {
      int row = j * 128 + (tid >> 2);
      __builtin_amdgcn_global_load_lds(
          (const AS1 void*)(Bp + (size_t)(n0 + row) * K + k0 + src_off),
          (AS3 void*)(&Bs[buf][row * 32 + (tid & 3) * 8]), 16, 0, 0);
    }
  };

  const int r15 = lane & 15, klog = lane >> 4;
  const int nt = K >> 5;                        // 24 K-tiles at K=768
  stage(0, 0); stage(1, 32); stage(2, 64);      // 3-deep prologue

  for (int t = 0; t < nt; ++t) {
    // gate: drain tile t's loads (t+1, t+2 stay in flight)
    if constexpr (BMBLK == 2) {
      if (t + 3 <= nt)      asm volatile("s_waitcnt vmcnt(8)" ::: "memory");
      else if (t + 2 == nt) asm volatile("s_waitcnt vmcnt(4)" ::: "memory");
      else                  asm volatile("s_waitcnt vmcnt(0)" ::: "memory");
    } else {
      if (t + 3 <= nt)      asm volatile("s_waitcnt vmcnt(6)" ::: "memory");
      else if (t + 2 == nt) asm volatile("s_waitcnt vmcnt(3)" ::: "memory");
      else                  asm volatile("s_waitcnt vmcnt(0)" ::: "memory");
    }
    __builtin_amdgcn_s_barrier();
    if (t + 3 < nt) stage((t + 3) & 3, (t + 3) << 5);   // disjoint ring slot

    const unsigned short* Ab = &As[t & 3][0];
    const unsigned short* Bb = &Bs[t & 3][0];
    s16x8 af[MI], bf[4];
#pragma unroll
    for (int i = 0; i < MI; ++i) {
      int row = wr * (BM / 2) + i * 16 + r15;
      int cp = klog ^ ((row & 3) ^ ((row >> 2) & 3));
      af[i] = *(const s16x8*)(Ab + row * 32 + cp * 8);
    }
#pragma unroll
    for (int j = 0; j < 4; ++j) {
      int row = wc * 64 + j * 16 + r15;
      int cp = klog ^ ((row & 3) ^ ((row >> 2) & 3));
      bf[j] = *(const s16x8*)(Bb + row * 32 + cp * 8);
    }
    __builtin_amdgcn_s_setprio(1);
#pragma unroll
    for (int i = 0; i < MI; ++i)
#pragma unroll
      for (int j = 0; j < 4; ++j)
        acc[i][j] = __builtin_amdgcn_mfma_f32_16x16x32_bf16(af[i], bf[j], acc[i][j], 0, 0, 0);
    __builtin_amdgcn_s_setprio(0);
  }

  // ---------------- epilogue ----------------
  const int g = lane >> 4, c15 = lane & 15;
  float bj[4];
#pragma unroll
  for (int j = 0; j < 4; ++j) bj[j] = bias[n0 + wc * 64 + j * 16 + c15];

  if (MODE == 0) {
    float* out = (float*)out0;
#pragma unroll
    for (int mi = 0; mi < MI; ++mi)
#pragma unroll
      for (int j = 0; j < 4; ++j) {
        int gr = m0 + wr * (BM / 2) + mi * 16 + g * 4;
        int gc = n0 + wc * 64 + j * 16 + c15;
#pragma unroll
        for (int r = 0; r < 4; ++r)
          out[(size_t)(gr + r) * N + gc] = acc[mi][j][r] + bj[j];
      }
  } else {
    if (n0 < 768) {            // q block: per-row softmax over this wave's 64 cols (one head)
      unsigned short* qsm = (unsigned short*)out0;
      const int cbase = n0 + wc * 64;
#pragma unroll
      for (int mi = 0; mi < MI; ++mi) {
#pragma unroll
        for (int r = 0; r < 4; ++r) {
          int gr = m0 + wr * (BM / 2) + mi * 16 + g * 4 + r;
          float v[4];
#pragma unroll
          for (int j = 0; j < 4; ++j) v[j] = acc[mi][j][r] + bj[j];
          float mx = fmaxf(fmaxf(v[0], v[1]), fmaxf(v[2], v[3]));
#pragma unroll
          for (int st = 1; st < 16; st <<= 1) mx = fmaxf(mx, __shfl_xor(mx, st));
          float p[4], sm = 0.f;
#pragma unroll
          for (int j = 0; j < 4; ++j) { p[j] = __expf(v[j] - mx); sm += p[j]; }
#pragma unroll
          for (int st = 1; st < 16; st <<= 1) sm += __shfl_xor(sm, st);
          float inv = 1.0f / sm;
#pragma unroll
          for (int j = 0; j < 4; ++j)
            qsm[(size_t)gr * 768 + cbase + j * 16 + c15] = f2bf(p[j] * inv);
        }
      }
    } else {                   // k or v block: fp16 compact store
      _Float16* dst = (n0 < 1536) ? (_Float16*)out1 : (_Float16*)out2;
      const int cbase = (n0 < 1536 ? n0 - 768 : n0 - 1536) + wc * 64;
#pragma unroll
      for (int mi = 0; mi < MI; ++mi)
#pragma unroll
        for (int j = 0; j < 4; ++j) {
          int gr = m0 + wr * (BM / 2) + mi * 16 + g * 4;
          int cc = cbase + j * 16 + c15;
#pragma unroll
          for (int r = 0; r < 4; ++r)
            dst[(size_t)(gr + r) * 768 + cc] = (_Float16)(acc[mi][j][r] + bj[j]);
        }
    }
  }
}

// ---------------- KV partial (no atomics): kv_part[split][bh][d][e], z_part ----------------
__global__ __launch_bounds__(256) void kv_partial(const _Float16* __restrict__ kh,
                                                  const _Float16* __restrict__ vh,
                                                  float* __restrict__ kv_part,
                                                  float* __restrict__ z_part) {
  const int bh = blockIdx.x, b = bh / 12, h = bh % 12;
  const int split = blockIdx.y;
  __shared__ float ek_s[64][68];
  __shared__ float v_s[64][68];
  __shared__ float zred[4][64];
  const int t = threadIdx.x;
  const int d0 = (t >> 4) * 4, e0 = (t & 15) * 4;
  const int zd = t & 63, zq = t >> 6;
  float acc[4][4] = {};
  float zp = 0.f;
  const size_t base = (size_t)b * 4096 * 768 + h * 64;

  for (int nc = 0; nc < 8; ++nc) {
    int n0 = split * 512 + nc * 64;
#pragma unroll
    for (int j = 0; j < 2; ++j) {
      int vi = t + j * 256;
      int row = vi >> 3, c8 = (vi & 7) * 8;
      size_t gp = base + (size_t)(n0 + row) * 768 + c8;
      f16x8 k8 = *(const f16x8*)(kh + gp);
      f16x8 v8 = *(const f16x8*)(vh + gp);
      f32x4 e0v, e1v, v0v, v1v;
#pragma unroll
      for (int u = 0; u < 4; ++u) {
        e0v[u] = __expf((float)k8[u]); e1v[u] = __expf((float)k8[4 + u]);
        v0v[u] = (float)v8[u];         v1v[u] = (float)v8[4 + u];
      }
      *(f32x4*)&ek_s[row][c8] = e0v; *(f32x4*)&ek_s[row][c8 + 4] = e1v;
      *(f32x4*)&v_s[row][c8]  = v0v; *(f32x4*)&v_s[row][c8 + 4]  = v1v;
    }
    __syncthreads();
#pragma unroll 4
    for (int r = 0; r < 16; ++r) zp += ek_s[zq * 16 + r][zd];
#pragma unroll 8
    for (int n = 0; n < 64; ++n) {
      f32x4 ekv = *(const f32x4*)&ek_s[n][d0];
      f32x4 vv  = *(const f32x4*)&v_s[n][e0];
#pragma unroll
      for (int i = 0; i < 4; ++i)
#pragma unroll
        for (int j = 0; j < 4; ++j)
          acc[i][j] += ekv[i] * vv[j];
    }
    __syncthreads();
  }
  float* kvp = kv_part + ((size_t)split * 96 + bh) * 4096;
#pragma unroll
  for (int i = 0; i < 4; ++i)
#pragma unroll
    for (int j = 0; j < 4; ++j)
      kvp[(d0 + i) * 64 + e0 + j] = acc[i][j];
  zred[zq][zd] = zp;
  __syncthreads();
  if (t < 64)
    z_part[((size_t)split * 96 + bh) * 64 + t] =
        zred[0][t] + zred[1][t] + zred[2][t] + zred[3][t];
}

// ---------------- Weff: weffT[b][c][h*64+d] = sum_e kv_n[b,h,d,e] * Wp[c][h*64+e] ----------------
__global__ __launch_bounds__(256) void weff_build(const float* __restrict__ kv_part,
                                                  const float* __restrict__ z_part,
                                                  const float* __restrict__ Wp,
                                                  unsigned short* __restrict__ weffT) {
  const int c0 = blockIdx.x * 64, h = blockIdx.y, b = blockIdx.z;
  const int bh = b * 12 + h;
  __shared__ float kvn[64][65];
  __shared__ float zs[64];
  const int t = threadIdx.x;
  if (t < 64) {
    float s = 0.f;
#pragma unroll
    for (int sp = 0; sp < 8; ++sp) s += z_part[((size_t)sp * 96 + bh) * 64 + t];
    zs[t] = s * 8.0f;                       // fold /sqrt(D)
  }
  __syncthreads();
#pragma unroll
  for (int i = 0; i < 16; ++i) {
    int idx = t + i * 256;
    int d = idx >> 6;
    float s = 0.f;
#pragma unroll
    for (int sp = 0; sp < 8; ++sp) s += kv_part[((size_t)sp * 96 + bh) * 4096 + idx];
    kvn[d][idx & 63] = s / zs[d];
  }
  __syncthreads();
  const int c = c0 + (t >> 2);
  const int d0 = (t & 3) * 16;
  const float* wrow = Wp + (size_t)c * 768 + h * 64;
  float acc[16] = {};
#pragma unroll 8
  for (int e = 0; e < 64; ++e) {
    float w = wrow[e];
#pragma unroll
    for (int dd = 0; dd < 16; ++dd) acc[dd] += w * kvn[d0 + dd][e];
  }
  unsigned short* orow = weffT + (size_t)b * 589824 + (size_t)c * 768 + h * 64 + d0;
#pragma unroll
  for (int dd = 0; dd < 16; ++dd) orow[dd] = f2bf(acc[dd]);
}

// ---------------- launch ----------------
extern "C" void kernel_launch(void* const* d_in, const int* in_sizes, int n_in,
                              void* d_out, int out_size, void* d_ws, size_t ws_size,
                              hipStream_t stream) {
  const float* x  = (const float*)d_in[0];
  const float* Wq = (const float*)d_in[1];
  const float* bq = (const float*)d_in[2];
  const float* Wk = (const float*)d_in[3];
  const float* bk = (const float*)d_in[4];
  const float* Wv = (const float*)d_in[5];
  const float* bv = (const float*)d_in[6];
  const float* Wp = (const float*)d_in[7];
  const float* bp = (const float*)d_in[8];

  const size_t MT = 32768;
  const size_t XE = MT * 768;
  const size_t WE = 768 * 768;

  unsigned short* x_bf    = (unsigned short*)d_ws;           // 48 MB
  unsigned short* wqkv_bf = x_bf + XE;                        // 3.4 MB
  unsigned short* q_sm    = wqkv_bf + 3 * WE;                 // 48 MB (bf16 softmaxed q)
  _Float16* k_h = (_Float16*)(q_sm + XE);                     // 48 MB
  _Float16* v_h = k_h + XE;                                   // 48 MB
  unsigned short* weffT = (unsigned short*)(v_h + XE);        // 9.4 MB
  float* bqkv    = (float*)(weffT + 8 * WE);                  // 9 KB
  float* kv_part = bqkv + 2304;                               // 12.6 MB (8 splits)
  float* z_part  = kv_part + (size_t)8 * 96 * 4096;           // 196 KB

  prep<<<2313, 256, 0, stream>>>(x, Wq, Wk, Wv, bq, bk, bv, x_bf, wqkv_bf, bqkv);

  // fused QKV GEMM: [32768,768] x [2304,768]^T ; epilogue q-softmax / k,v fp16
  gemm_rb<1, 2><<<1152, 512, 0, stream>>>(x_bf, wqkv_bf, bqkv, q_sm, k_h, v_h, 2304, 768, 9, 0);

  kv_partial<<<dim3(96, 8), 256, 0, stream>>>(k_h, v_h, kv_part, z_part);
  weff_build<<<dim3(12, 12, 8), 256, 0, stream>>>(kv_part, z_part, Wp, weffT);

  // out = q_sm @ Weff_b^T + bp  (BM=128: 768 blocks = 3 exact rounds)
  gemm_rb<0, 1><<<768, 512, 0, stream>>>(q_sm, weffT, bp, d_out, nullptr, nullptr, 768, 768, 3, 1);
}

// Round 9
// 319.452 us; speedup vs baseline: 1.1919x; 1.1919x over previous
//
#include <hip/hip_runtime.h>
#include <hip/hip_bf16.h>

// EfficientAttention: B=8 N=4096 C=768 H=12 D=64, M = 32768
// prep (cast + bias) -> gemm128<QKV> (q-softmax epilogue; k,v fp16)
//   -> kv_partial (private split buffers) -> weff_build -> gemm128<OUT>
// R9 GEMM: m97-exact geometry — 128x128 tile, 4 waves (2x2, per-wave 64x64),
// BK=64, SINGLE-buffered 32KB LDS, 2 barriers/tile. acc=64 AGPR -> ~160 unified
// regs -> 3 blocks/CU: the vmcnt drain + DS skew overlap across blocks (m114),
// which the 1-block/CU 256^2 variants could not do. R4's verified 0-conflict
// swizzle (128B rows) + T1 XCD swizzle (m-major) + fused N=2304 carried over.
// No setprio (m190: negative on this structure).

#define AS1 __attribute__((address_space(1)))
#define AS3 __attribute__((address_space(3)))

typedef __attribute__((ext_vector_type(8))) short    s16x8;
typedef __attribute__((ext_vector_type(4))) float    f32x4;
typedef __attribute__((ext_vector_type(8))) _Float16 f16x8;
typedef __attribute__((ext_vector_type(4))) unsigned short u16x4;

__device__ __forceinline__ unsigned short f2bf(float f) {
  union { float f; unsigned u; } v; v.f = f;
  unsigned r = v.u + 0x7FFFu + ((v.u >> 16) & 1u);
  return (unsigned short)(r >> 16);
}

// ---------------- prep: cast x + Wq|Wk|Wv -> bf16, concat bias ----------------
__global__ __launch_bounds__(256) void prep(const float* __restrict__ x,
                                            const float* __restrict__ Wq, const float* __restrict__ Wk,
                                            const float* __restrict__ Wv,
                                            const float* __restrict__ bq, const float* __restrict__ bk,
                                            const float* __restrict__ bv,
                                            unsigned short* __restrict__ x_bf,
                                            unsigned short* __restrict__ wqkv_bf,
                                            float* __restrict__ bqkv) {
  const int XB = 2304;
  if ((int)blockIdx.x >= XB) {                    // 9 tail blocks: bias concat
    int j = (blockIdx.x - XB) * 256 + threadIdx.x;
    if (j < 768) bqkv[j] = bq[j];
    else if (j < 1536) bqkv[j] = bk[j - 768];
    else if (j < 2304) bqkv[j] = bv[j - 1536];
    return;
  }
  const int n8x = 3145728, n8w = 73728;
  const int stride = XB * 256;
  for (int i = blockIdx.x * 256 + threadIdx.x; i < n8x + 3 * n8w; i += stride) {
    const float* s; unsigned short* d;
    if (i < n8x) { s = x + (size_t)i * 8; d = x_bf + (size_t)i * 8; }
    else {
      int wi = i - n8x, w = wi / n8w, off = wi - w * n8w;
      const float* ws_ = (w == 0) ? Wq : (w == 1) ? Wk : Wv;
      s = ws_ + (size_t)off * 8; d = wqkv_bf + (size_t)wi * 8;
    }
    f32x4 a = ((const f32x4*)s)[0], b = ((const f32x4*)s)[1];
    u16x4 lo, hi;
    lo[0] = f2bf(a[0]); lo[1] = f2bf(a[1]); lo[2] = f2bf(a[2]); lo[3] = f2bf(a[3]);
    hi[0] = f2bf(b[0]); hi[1] = f2bf(b[1]); hi[2] = f2bf(b[2]); hi[3] = f2bf(b[3]);
    ((u16x4*)d)[0] = lo; ((u16x4*)d)[1] = hi;
  }
}

// ---------------- gemm128: C[M,N] = A[M,K] @ Bm[N,K]^T + bias ----------------
// m97 structure. MODE 0: fp32 out (batched B). MODE 1: QKV epilogue.
template <int MODE>
__global__ __launch_bounds__(256, 3) void gemm128(const unsigned short* __restrict__ A,
                                                  const unsigned short* __restrict__ Bm,
                                                  const float* __restrict__ bias,
                                                  void* out0, void* out1, void* out2,
                                                  int N, int K, int nb, int batchedB) {
  __shared__ unsigned short As[128 * 64];
  __shared__ unsigned short Bs[128 * 64];
  const int tid = threadIdx.x, lane = tid & 63, wid = tid >> 6;
  const int wm = wid >> 1, wn = wid & 1;
  const int cpx = gridDim.x >> 3;
  const int logical = (blockIdx.x & 7) * cpx + (blockIdx.x >> 3);
  const int m0 = (logical / nb) * 128, n0 = (logical % nb) * 128;
  const unsigned short* Bp = Bm + (batchedB ? ((size_t)(m0 >> 12) * 589824) : 0);

  f32x4 acc[4][4] = {};
  const int srcc8 = ((tid & 7) ^ ((tid >> 3) & 7)) * 8;   // T2 pre-swizzled source col
  const int r15 = lane & 15, hi8 = (lane >> 4) * 8, sw = (lane & 7) * 8;

  const int nt = K >> 6;
  for (int t = 0; t < nt; ++t) {
    const int k0 = t << 6;
#pragma unroll
    for (int j = 0; j < 4; ++j) {                 // 4 A-loads + 4 B-loads / thread
      int row = j * 32 + (tid >> 3);
      __builtin_amdgcn_global_load_lds(
          (const AS1 void*)(A + (size_t)(m0 + row) * K + k0 + srcc8),
          (AS3 void*)(&As[row * 64 + (tid & 7) * 8]), 16, 0, 0);
      __builtin_amdgcn_global_load_lds(
          (const AS1 void*)(Bp + (size_t)(n0 + row) * K + k0 + srcc8),
          (AS3 void*)(&Bs[row * 64 + (tid & 7) * 8]), 16, 0, 0);
    }
    __syncthreads();                              // full drain (m97); TLP covers
#pragma unroll
    for (int kk = 0; kk < 2; ++kk) {
      s16x8 af[4], bf[4];
#pragma unroll
      for (int i = 0; i < 4; ++i)
        af[i] = *(const s16x8*)(As + (wm * 64 + i * 16 + r15) * 64 + ((kk * 32 + hi8) ^ sw));
#pragma unroll
      for (int j = 0; j < 4; ++j)
        bf[j] = *(const s16x8*)(Bs + (wn * 64 + j * 16 + r15) * 64 + ((kk * 32 + hi8) ^ sw));
#pragma unroll
      for (int i = 0; i < 4; ++i)
#pragma unroll
        for (int j = 0; j < 4; ++j)
          acc[i][j] = __builtin_amdgcn_mfma_f32_16x16x32_bf16(af[i], bf[j], acc[i][j], 0, 0, 0);
    }
    __syncthreads();
  }

  // ---------------- epilogue ----------------
  const int g = lane >> 4, c15 = lane & 15;
  float bj[4];
#pragma unroll
  for (int j = 0; j < 4; ++j) bj[j] = bias[n0 + wn * 64 + j * 16 + c15];

  if (MODE == 0) {
    float* out = (float*)out0;
#pragma unroll
    for (int mi = 0; mi < 4; ++mi)
#pragma unroll
      for (int j = 0; j < 4; ++j) {
        int gr = m0 + wm * 64 + mi * 16 + g * 4;
        int gc = n0 + wn * 64 + j * 16 + c15;
#pragma unroll
        for (int r = 0; r < 4; ++r)
          out[(size_t)(gr + r) * N + gc] = acc[mi][j][r] + bj[j];
      }
  } else {
    if (n0 < 768) {            // q block: per-row softmax over this wave's 64 cols (one head)
      unsigned short* qsm = (unsigned short*)out0;
      const int cbase = n0 + wn * 64;
#pragma unroll
      for (int mi = 0; mi < 4; ++mi) {
#pragma unroll
        for (int r = 0; r < 4; ++r) {
          int gr = m0 + wm * 64 + mi * 16 + g * 4 + r;
          float v[4];
#pragma unroll
          for (int j = 0; j < 4; ++j) v[j] = acc[mi][j][r] + bj[j];
          float mx = fmaxf(fmaxf(v[0], v[1]), fmaxf(v[2], v[3]));
#pragma unroll
          for (int st = 1; st < 16; st <<= 1) mx = fmaxf(mx, __shfl_xor(mx, st));
          float p[4], sm = 0.f;
#pragma unroll
          for (int j = 0; j < 4; ++j) { p[j] = __expf(v[j] - mx); sm += p[j]; }
#pragma unroll
          for (int st = 1; st < 16; st <<= 1) sm += __shfl_xor(sm, st);
          float inv = 1.0f / sm;
#pragma unroll
          for (int j = 0; j < 4; ++j)
            qsm[(size_t)gr * 768 + cbase + j * 16 + c15] = f2bf(p[j] * inv);
        }
      }
    } else {                   // k or v block: fp16 compact store
      _Float16* dst = (n0 < 1536) ? (_Float16*)out1 : (_Float16*)out2;
      const int cbase = (n0 < 1536 ? n0 - 768 : n0 - 1536) + wn * 64;
#pragma unroll
      for (int mi = 0; mi < 4; ++mi)
#pragma unroll
        for (int j = 0; j < 4; ++j) {
          int gr = m0 + wm * 64 + mi * 16 + g * 4;
          int cc = cbase + j * 16 + c15;
#pragma unroll
          for (int r = 0; r < 4; ++r)
            dst[(size_t)(gr + r) * 768 + cc] = (_Float16)(acc[mi][j][r] + bj[j]);
        }
    }
  }
}

// ---------------- KV partial (no atomics): kv_part[split][bh][d][e], z_part ----------------
__global__ __launch_bounds__(256) void kv_partial(const _Float16* __restrict__ kh,
                                                  const _Float16* __restrict__ vh,
                                                  float* __restrict__ kv_part,
                                                  float* __restrict__ z_part) {
  const int bh = blockIdx.x, b = bh / 12, h = bh % 12;
  const int split = blockIdx.y;
  __shared__ float ek_s[64][68];
  __shared__ float v_s[64][68];
  __shared__ float zred[4][64];
  const int t = threadIdx.x;
  const int d0 = (t >> 4) * 4, e0 = (t & 15) * 4;
  const int zd = t & 63, zq = t >> 6;
  float acc[4][4] = {};
  float zp = 0.f;
  const size_t base = (size_t)b * 4096 * 768 + h * 64;

  for (int nc = 0; nc < 8; ++nc) {
    int n0 = split * 512 + nc * 64;
#pragma unroll
    for (int j = 0; j < 2; ++j) {
      int vi = t + j * 256;
      int row = vi >> 3, c8 = (vi & 7) * 8;
      size_t gp = base + (size_t)(n0 + row) * 768 + c8;
      f16x8 k8 = *(const f16x8*)(kh + gp);
      f16x8 v8 = *(const f16x8*)(vh + gp);
      f32x4 e0v, e1v, v0v, v1v;
#pragma unroll
      for (int u = 0; u < 4; ++u) {
        e0v[u] = __expf((float)k8[u]); e1v[u] = __expf((float)k8[4 + u]);
        v0v[u] = (float)v8[u];         v1v[u] = (float)v8[4 + u];
      }
      *(f32x4*)&ek_s[row][c8] = e0v; *(f32x4*)&ek_s[row][c8 + 4] = e1v;
      *(f32x4*)&v_s[row][c8]  = v0v; *(f32x4*)&v_s[row][c8 + 4]  = v1v;
    }
    __syncthreads();
#pragma unroll 4
    for (int r = 0; r < 16; ++r) zp += ek_s[zq * 16 + r][zd];
#pragma unroll 8
    for (int n = 0; n < 64; ++n) {
      f32x4 ekv = *(const f32x4*)&ek_s[n][d0];
      f32x4 vv  = *(const f32x4*)&v_s[n][e0];
#pragma unroll
      for (int i = 0; i < 4; ++i)
#pragma unroll
        for (int j = 0; j < 4; ++j)
          acc[i][j] += ekv[i] * vv[j];
    }
    __syncthreads();
  }
  float* kvp = kv_part + ((size_t)split * 96 + bh) * 4096;
#pragma unroll
  for (int i = 0; i < 4; ++i)
#pragma unroll
    for (int j = 0; j < 4; ++j)
      kvp[(d0 + i) * 64 + e0 + j] = acc[i][j];
  zred[zq][zd] = zp;
  __syncthreads();
  if (t < 64)
    z_part[((size_t)split * 96 + bh) * 64 + t] =
        zred[0][t] + zred[1][t] + zred[2][t] + zred[3][t];
}

// ---------------- Weff: weffT[b][c][h*64+d] = sum_e kv_n[b,h,d,e] * Wp[c][h*64+e] ----------------
__global__ __launch_bounds__(256) void weff_build(const float* __restrict__ kv_part,
                                                  const float* __restrict__ z_part,
                                                  const float* __restrict__ Wp,
                                                  unsigned short* __restrict__ weffT) {
  const int c0 = blockIdx.x * 64, h = blockIdx.y, b = blockIdx.z;
  const int bh = b * 12 + h;
  __shared__ float kvn[64][65];
  __shared__ float zs[64];
  const int t = threadIdx.x;
  if (t < 64) {
    float s = 0.f;
#pragma unroll
    for (int sp = 0; sp < 8; ++sp) s += z_part[((size_t)sp * 96 + bh) * 64 + t];
    zs[t] = s * 8.0f;                       // fold /sqrt(D)
  }
  __syncthreads();
#pragma unroll
  for (int i = 0; i < 16; ++i) {
    int idx = t + i * 256;
    int d = idx >> 6;
    float s = 0.f;
#pragma unroll
    for (int sp = 0; sp < 8; ++sp) s += kv_part[((size_t)sp * 96 + bh) * 4096 + idx];
    kvn[d][idx & 63] = s / zs[d];
  }
  __syncthreads();
  const int c = c0 + (t >> 2);
  const int d0 = (t & 3) * 16;
  const float* wrow = Wp + (size_t)c * 768 + h * 64;
  float acc[16] = {};
#pragma unroll 8
  for (int e = 0; e < 64; ++e) {
    float w = wrow[e];
#pragma unroll
    for (int dd = 0; dd < 16; ++dd) acc[dd] += w * kvn[d0 + dd][e];
  }
  unsigned short* orow = weffT + (size_t)b * 589824 + (size_t)c * 768 + h * 64 + d0;
#pragma unroll
  for (int dd = 0; dd < 16; ++dd) orow[dd] = f2bf(acc[dd]);
}

// ---------------- launch ----------------
extern "C" void kernel_launch(void* const* d_in, const int* in_sizes, int n_in,
                              void* d_out, int out_size, void* d_ws, size_t ws_size,
                              hipStream_t stream) {
  const float* x  = (const float*)d_in[0];
  const float* Wq = (const float*)d_in[1];
  const float* bq = (const float*)d_in[2];
  const float* Wk = (const float*)d_in[3];
  const float* bk = (const float*)d_in[4];
  const float* Wv = (const float*)d_in[5];
  const float* bv = (const float*)d_in[6];
  const float* Wp = (const float*)d_in[7];
  const float* bp = (const float*)d_in[8];

  const size_t MT = 32768;
  const size_t XE = MT * 768;
  const size_t WE = 768 * 768;

  unsigned short* x_bf    = (unsigned short*)d_ws;           // 48 MB
  unsigned short* wqkv_bf = x_bf + XE;                        // 3.4 MB
  unsigned short* q_sm    = wqkv_bf + 3 * WE;                 // 48 MB (bf16 softmaxed q)
  _Float16* k_h = (_Float16*)(q_sm + XE);                     // 48 MB
  _Float16* v_h = k_h + XE;                                   // 48 MB
  unsigned short* weffT = (unsigned short*)(v_h + XE);        // 9.4 MB
  float* bqkv    = (float*)(weffT + 8 * WE);                  // 9 KB
  float* kv_part = bqkv + 2304;                               // 12.6 MB (8 splits)
  float* z_part  = kv_part + (size_t)8 * 96 * 4096;           // 196 KB

  prep<<<2313, 256, 0, stream>>>(x, Wq, Wk, Wv, bq, bk, bv, x_bf, wqkv_bf, bqkv);

  // fused QKV GEMM: [32768,768] x [2304,768]^T ; epilogue q-softmax / k,v fp16
  gemm128<1><<<4608, 256, 0, stream>>>(x_bf, wqkv_bf, bqkv, q_sm, k_h, v_h, 2304, 768, 18, 0);

  kv_partial<<<dim3(96, 8), 256, 0, stream>>>(k_h, v_h, kv_part, z_part);
  weff_build<<<dim3(12, 12, 8), 256, 0, stream>>>(kv_part, z_part, Wp, weffT);

  // out = q_sm @ Weff_b^T + bp
  gemm128<0><<<1536, 256, 0, stream>>>(q_sm, weffT, bp, d_out, nullptr, nullptr, 768, 768, 6, 1);
}